// Round 2
// baseline (119.570 us; speedup 1.0000x reference)
//
#include <hip/hip_runtime.h>
#include <cmath>

// Problem constants (from reference): N=2, Lq=1024, Lk=1024, H=8, d=64, P=1, D=512
#define NB    2
#define LSEQ  1024
#define NH    8
#define HD    64
#define DD    512    // NH*HD
#define FDIM  128    // 2*HD  (cos|sin features)
#define EV    65     // HD + 1 (values + denominator unit column)
#define SEP   80     // padded e-extent of the stored chunk state
#define CHUNK 64
#define NC    16     // LSEQ / CHUNK
#define NBH   16     // NB*NH

typedef short short8 __attribute__((ext_vector_type(8)));   // 8 bf16 (4 VGPRs)
typedef short short4_t __attribute__((ext_vector_type(4))); // 4 bf16 (8B store)
typedef float floatx4 __attribute__((ext_vector_type(4)));  // MFMA C/D frag
typedef unsigned short ushort;

__device__ __forceinline__ float softplusf(float x) {
  return fmaxf(x, 0.0f) + log1pf(expf(-fabsf(x)));
}

__device__ __forceinline__ ushort f2bf(float f) {
  unsigned u = __float_as_uint(f);
  u += 0x7fffu + ((u >> 16) & 1u);
  return (ushort)(u >> 16);
}

__device__ __forceinline__ short8 cvt8(float4 a, float4 b) {
  short8 r;
  r[0] = (short)f2bf(a.x); r[1] = (short)f2bf(a.y);
  r[2] = (short)f2bf(a.z); r[3] = (short)f2bf(a.w);
  r[4] = (short)f2bf(b.x); r[5] = (short)f2bf(b.y);
  r[6] = (short)f2bf(b.z); r[7] = (short)f2bf(b.w);
  return r;
}

// ---------------------------------------------------------------------------
// K0: one-shot fp32 -> bf16 conversion of all GEMM operands.
// 8-float groups: Xq 131072, Xkv 131072, Wq/Wk/Wv 32768 each = 360448 total.
// ---------------------------------------------------------------------------
__global__ __launch_bounds__(256) void k_cvt(
    const float* __restrict__ Xq, const float* __restrict__ Xkv,
    const float* __restrict__ Wq, const float* __restrict__ Wk,
    const float* __restrict__ Wv,
    ushort* __restrict__ Xqb, ushort* __restrict__ Xkvb,
    ushort* __restrict__ Wqb, ushort* __restrict__ Wkb,
    ushort* __restrict__ Wvb)
{
  const int i = blockIdx.x * 256 + threadIdx.x;
  const float* src; ushort* dst; int g;
  if (i < 131072)      { src = Xq;  dst = Xqb;  g = i; }
  else if (i < 262144) { src = Xkv; dst = Xkvb; g = i - 131072; }
  else if (i < 294912) { src = Wq;  dst = Wqb;  g = i - 262144; }
  else if (i < 327680) { src = Wk;  dst = Wkb;  g = i - 294912; }
  else                 { src = Wv;  dst = Wvb;  g = i - 327680; }
  const float4 a = ((const float4*)src)[(size_t)g * 2];
  const float4 b = ((const float4*)src)[(size_t)g * 2 + 1];
  *(short8*)&dst[(size_t)g * 8] = cvt8(a, b);
}

// ---------------------------------------------------------------------------
// K1: ALL projections, bf16 MFMA, K-slice 64, 64x64 tiles, 768 blocks,
// LDS double-buffered, ONE barrier per K-slice, bf16 operands, XCD-chunked
// blockIdx swizzle. (Unchanged from the 111.0 us config.)
// ---------------------------------------------------------------------------
__global__ __launch_bounds__(256) void k_proj(
    const ushort* __restrict__ Xqb, const ushort* __restrict__ Xkvb,
    const ushort* __restrict__ Wqb, const ushort* __restrict__ Wkb,
    const ushort* __restrict__ Wvb,
    const float* __restrict__ pw, const float* __restrict__ pb,
    const float* __restrict__ pc,
    ushort* __restrict__ Qfb, ushort* __restrict__ Kfb,
    ushort* __restrict__ Vxb)
{
  __shared__ short Al[2][64][72];   // [buf][m][k] bf16
  __shared__ short Bl[2][64][72];   // [buf][e][k] bf16
  const int b = ((blockIdx.x & 7) * 96) + (blockIdx.x >> 3);
  int m0, e0, pmode;             // 0 = q, 1 = k, 2 = v
  const ushort *X, *W;
  if (b < 256) {
    m0 = (b >> 3) << 6; e0 = (b & 7) << 6;
    X = Xqb; W = Wqb + (size_t)e0 * DD; pmode = 0;
  } else {
    const int bb = b - 256;
    m0 = (bb >> 4) << 6;
    const int nt = bb & 15;
    e0 = (nt & 7) << 6;
    X = Xkvb;
    if (nt < 8) { W = Wkb + (size_t)e0 * DD; pmode = 1; }
    else        { W = Wvb + (size_t)e0 * DD; pmode = 2; }
  }
  const int tid  = threadIdx.x;
  const int r    = tid >> 2;               // staging row 0..63
  const int ko   = (tid & 3) << 4;         // 0,16,32,48 shorts
  const int wave = tid >> 6, lane = tid & 63;
  const int quad = lane >> 4, lm = lane & 15;
  const ushort* Ag = X + (size_t)(m0 + r) * DD + ko;
  const ushort* Bg = W + (size_t)r * DD + ko;

  short8 a0 = *(const short8*)(Ag);
  short8 a1 = *(const short8*)(Ag + 8);
  short8 b0 = *(const short8*)(Bg);
  short8 b1 = *(const short8*)(Bg + 8);
  *(short8*)&Al[0][r][ko]     = a0;
  *(short8*)&Al[0][r][ko + 8] = a1;
  *(short8*)&Bl[0][r][ko]     = b0;
  *(short8*)&Bl[0][r][ko + 8] = b1;
  __syncthreads();

  floatx4 acc[4] = {};
  for (int k0 = 0; k0 < DD; k0 += 64) {
    const int cur  = (k0 >> 6) & 1;
    const bool more = (k0 + 64 < DD);
    if (more) {
      a0 = *(const short8*)(Ag + k0 + 64);
      a1 = *(const short8*)(Ag + k0 + 72);
      b0 = *(const short8*)(Bg + k0 + 64);
      b1 = *(const short8*)(Bg + k0 + 72);
    }
#pragma unroll
    for (int ks = 0; ks < 2; ++ks) {
      const short8 af = *(const short8*)&Al[cur][(wave << 4) + lm][(quad << 3) + (ks << 5)];
#pragma unroll
      for (int t = 0; t < 4; ++t) {
        const short8 bf = *(const short8*)&Bl[cur][(t << 4) + lm][(quad << 3) + (ks << 5)];
        acc[t] = __builtin_amdgcn_mfma_f32_16x16x32_bf16(af, bf, acc[t], 0, 0, 0);
      }
    }
    if (more) {
      const int nxt = cur ^ 1;
      *(short8*)&Al[nxt][r][ko]     = a0;
      *(short8*)&Al[nxt][r][ko + 8] = a1;
      *(short8*)&Bl[nxt][r][ko]     = b0;
      *(short8*)&Bl[nxt][r][ko + 8] = b1;
    }
    __syncthreads();
  }
#pragma unroll
  for (int t = 0; t < 4; ++t) {
    const int e = e0 + (t << 4) + lm;
    const int h = e >> 6, jj = e & 63;
    if (pmode == 2) {
#pragma unroll
      for (int rg = 0; rg < 4; ++rg) {
        const int m = m0 + (wave << 4) + (quad << 2) + rg;
        const int n = m >> 10, l = m & 1023;
        Vxb[((size_t)(n * NH + h) * LSEQ + l) * HD + jj] = f2bf(acc[t][rg]);
      }
    } else {
      const float pwv = pw[e];
      const float pbv = (pmode == 0) ? pb[e] : 0.0f;
      const float pcv = (pmode == 0) ? pc[e] : 1.0f;
      ushort* base = (pmode == 0) ? Qfb : Kfb;
#pragma unroll
      for (int rg = 0; rg < 4; ++rg) {
        const int m = m0 + (wave << 4) + (quad << 2) + rg;
        const int n = m >> 10, l = m & 1023;
        const float v = softplusf(acc[t][rg]) * pcv;
        const float ang = fmaf((float)l, pwv, pbv);
        ushort* dst = &base[((size_t)(n * NH + h) * LSEQ + l) * FDIM + jj];
        dst[0]  = f2bf(v * __cosf(ang));
        dst[64] = f2bf(v * __sinf(ang));
      }
    }
  }
}

// ---------------------------------------------------------------------------
// K23 (fused k_chunk_sums + k_scan): the MFMA accumulator IS the scan state.
// Grid 32 = (bh, f-half), 512 threads (8 waves: wq=wave&3 row-group of K^T,
// wn=wave>>2 splits the 5 e-tiles {0,1,2}/{3,4}). Per chunk: write the
// exclusive prefix (acc) straight to PTb as bf16, then acc += K_c^T @ Vext_c
// via in-place MFMA accumulation. Eliminates the 21 MB fp32 S round-trip and
// one kernel launch. Next chunk's K/V register-prefetched under the MFMA.
// ---------------------------------------------------------------------------
__global__ __launch_bounds__(512) void k_sums_scan(
    const ushort* __restrict__ Kfb, const ushort* __restrict__ Vxb,
    ushort* __restrict__ PTb)
{
  const int bh = blockIdx.x >> 1;
  const int fh = blockIdx.x & 1;
  const int f0 = fh << 6;
  const int tid  = threadIdx.x;
  const int wave = tid >> 6, lane = tid & 63;
  const int quad = lane >> 4, lm = lane & 15;
  const int wq = wave & 3, wn = wave >> 2;

  __shared__ short KT[64][72];   // [f-f0][t] bf16
  __shared__ short VT[80][72];   // [e][t]    bf16

  // one-time rows: unit col (e=64) and zero pad rows 65..79 (kept clean so
  // the nt=4 MFMA B-frag never reads uninitialized LDS across 16 chunks)
  if (tid < 64) VT[64][tid] = (short)0x3F80;   // bf16 1.0
  for (int i = tid; i < 15 * 64; i += 512) VT[65 + (i >> 6)][i & 63] = 0;

  // staging pattern: 512 threads = 64 t-cols x 8 col-groups, one vec each
  const int st  = tid & 63;
  const int sf8 = (tid >> 6) << 3;
  const ushort* Kg = &Kfb[(size_t)bh * LSEQ * FDIM + f0];
  const ushort* Vg = &Vxb[(size_t)bh * LSEQ * HD];

  short8 kr = *(const short8*)&Kg[(size_t)st * FDIM + sf8];
  short8 vr = *(const short8*)&Vg[(size_t)st * HD + sf8];
#pragma unroll
  for (int u = 0; u < 8; ++u) { KT[sf8 + u][st] = kr[u]; VT[sf8 + u][st] = vr[u]; }
  __syncthreads();

  const int NT0 = wn ? 3 : 0;   // first e-tile this wave owns
  const int NTN = wn ? 2 : 3;   // how many e-tiles
  const int fb  = f0 + (wq << 4) + (quad << 2);  // absolute f base for stores
  floatx4 acc[3] = {};

  for (int c = 0; c < NC; ++c) {
    const bool more = (c + 1 < NC);
    if (more) {
      const int tn = (c + 1) << 6;
      kr = *(const short8*)&Kg[(size_t)(tn + st) * FDIM + sf8];
      vr = *(const short8*)&Vg[(size_t)(tn + st) * HD + sf8];
    }
    // exclusive prefix out (acc = sum of chunks < c), bf16, 8B stores
    {
      ushort* Pg = &PTb[(size_t)(bh * NC + c) * SEP * FDIM];
#pragma unroll
      for (int j = 0; j < 3; ++j) if (j < NTN) {
        const int e = ((NT0 + j) << 4) + lm;
        short4_t p;
        p[0] = (short)f2bf(acc[j][0]); p[1] = (short)f2bf(acc[j][1]);
        p[2] = (short)f2bf(acc[j][2]); p[3] = (short)f2bf(acc[j][3]);
        *(short4_t*)&Pg[(size_t)e * FDIM + fb] = p;
      }
    }
    // accumulate this chunk's sum into acc (fp32 MFMA accumulation)
    short8 aK[2];
#pragma unroll
    for (int ks = 0; ks < 2; ++ks)
      aK[ks] = *(const short8*)&KT[(wq << 4) + lm][(quad << 3) + (ks << 5)];
#pragma unroll
    for (int j = 0; j < 3; ++j) if (j < NTN)
#pragma unroll
      for (int ks = 0; ks < 2; ++ks) {
        const short8 bf = *(const short8*)&VT[((NT0 + j) << 4) + lm][(quad << 3) + (ks << 5)];
        acc[j] = __builtin_amdgcn_mfma_f32_16x16x32_bf16(aK[ks], bf, acc[j], 0, 0, 0);
      }
    __syncthreads();
    if (more) {
#pragma unroll
      for (int u = 0; u < 8; ++u) { KT[sf8 + u][st] = kr[u]; VT[sf8 + u][st] = vr[u]; }
      __syncthreads();
    }
  }
}

// ---------------------------------------------------------------------------
// K4: per-chunk output, 512 threads / 8 waves: wq=wave&3 owns 16 q-rows,
// wn=wave>>2 splits output tiles (phase1 nt {0,1}/{2,3}; phases 2-3
// nt {0,1,2}/{3,4}). Shared LDS staging (no duplication), per-wave MFMA work
// halved, 16 waves/CU (was 4). Extra barriers: ScL and DenL are cross-wave.
// ---------------------------------------------------------------------------
__global__ __launch_bounds__(512) void k_chunk_out(
    const ushort* __restrict__ Qfb, const ushort* __restrict__ Kfb,
    const ushort* __restrict__ Vxb, const ushort* __restrict__ PTb,
    float* __restrict__ Out)
{
  const int c  = blockIdx.x & (NC - 1);
  const int bh = blockIdx.x >> 4;
  const int n  = bh >> 3, h = bh & 7;
  const int t0 = c * CHUNK;
  const int tid  = threadIdx.x;
  const int wave = tid >> 6, lane = tid & 63;
  const int quad = lane >> 4, lm = lane & 15;
  const int wq = wave & 3, wn = wave >> 2;

  __shared__ short QL[64][136];    // [t][f] bf16 (pad: 2-way banks)
  __shared__ short KL[64][136];    // [t][f] bf16
  __shared__ short ScL[64][72];    // [m][t] bf16
  __shared__ short PT[80][136];    // [e][f] bf16
  __shared__ short VT[80][72];     // [e][t] bf16
  __shared__ float DenL[64];

  const ushort* Qg = &Qfb[((size_t)bh * LSEQ + t0) * FDIM];
  const ushort* Kg = &Kfb[((size_t)bh * LSEQ + t0) * FDIM];
  for (int i = tid; i < 64 * 16; i += 512) {
    const int r = i >> 4, f8 = (i & 15) << 3;
    *(short8*)&QL[r][f8] = *(const short8*)&Qg[r * FDIM + f8];
    *(short8*)&KL[r][f8] = *(const short8*)&Kg[r * FDIM + f8];
  }
  {
    const ushort* Pg = &PTb[(size_t)(bh * NC + c) * SEP * FDIM];
    for (int i = tid; i < 65 * 16; i += 512) {
      const int e = i >> 4, f8 = (i & 15) << 3;
      *(short8*)&PT[e][f8] = *(const short8*)&Pg[e * FDIM + f8];
    }
  }
  for (int i = tid; i < 64 * 8; i += 512) {
    const int t = i & 63, e8 = (i >> 6) << 3;
    const short8 v8 = *(const short8*)&Vxb[((size_t)bh * LSEQ + t0 + t) * HD + e8];
#pragma unroll
    for (int u = 0; u < 8; ++u) VT[e8 + u][t] = v8[u];
  }
  if (tid < CHUNK) VT[64][tid] = (short)0x3F80;   // bf16 1.0
  __syncthreads();

  short8 aQ[4];
#pragma unroll
  for (int ks = 0; ks < 4; ++ks)
    aQ[ks] = *(const short8*)&QL[(wq << 4) + lm][(quad << 3) + (ks << 5)];

  // phase 1: scores; wave owns t-tiles nt = wn*2 + j
  floatx4 accS[2] = {};
#pragma unroll
  for (int j = 0; j < 2; ++j)
#pragma unroll
    for (int ks = 0; ks < 4; ++ks) {
      const short8 b = *(const short8*)&KL[(((wn << 1) + j) << 4) + lm][(quad << 3) + (ks << 5)];
      accS[j] = __builtin_amdgcn_mfma_f32_16x16x32_bf16(aQ[ks], b, accS[j], 0, 0, 0);
    }
#pragma unroll
  for (int j = 0; j < 2; ++j)
#pragma unroll
    for (int rg = 0; rg < 4; ++rg) {
      const int m = (wq << 4) + (quad << 2) + rg;
      const int t = (((wn << 1) + j) << 4) + lm;
      ScL[m][t] = (short)((t <= m) ? f2bf(accS[j][rg]) : 0);
    }

  // phase 2: num = Q @ P; wave owns e-tiles NT0..NT0+NTN-1 (no ScL dep)
  const int NT0 = wn ? 3 : 0;
  const int NTN = wn ? 2 : 3;
  floatx4 accN[3] = {};
#pragma unroll
  for (int j = 0; j < 3; ++j) if (j < NTN)
#pragma unroll
    for (int ks = 0; ks < 4; ++ks) {
      const short8 b = *(const short8*)&PT[((NT0 + j) << 4) + lm][(quad << 3) + (ks << 5)];
      accN[j] = __builtin_amdgcn_mfma_f32_16x16x32_bf16(aQ[ks], b, accN[j], 0, 0, 0);
    }

  __syncthreads();   // ScL now complete across waves

  // phase 3: PV = Sc @ Vext, same e-tile split as phase 2
  short8 aS[2];
#pragma unroll
  for (int ks = 0; ks < 2; ++ks)
    aS[ks] = *(const short8*)&ScL[(wq << 4) + lm][(quad << 3) + (ks << 5)];
  floatx4 accV[3] = {};
#pragma unroll
  for (int j = 0; j < 3; ++j) if (j < NTN)
#pragma unroll
    for (int ks = 0; ks < 2; ++ks) {
      const short8 b = *(const short8*)&VT[((NT0 + j) << 4) + lm][(quad << 3) + (ks << 5)];
      accV[j] = __builtin_amdgcn_mfma_f32_16x16x32_bf16(aS[ks], b, accV[j], 0, 0, 0);
    }

  // denominator tile is nt=4 -> wn==1, local j==1
  if (wn == 1 && lm == 0) {
#pragma unroll
    for (int rg = 0; rg < 4; ++rg)
      DenL[(wq << 4) + (quad << 2) + rg] = accN[1][rg] + accV[1][rg];
  }
  __syncthreads();   // DenL cross-wave

  const int nout = wn ? 1 : 3;   // wn0 writes nt 0,1,2; wn1 writes nt 3
#pragma unroll
  for (int rg = 0; rg < 4; ++rg) {
    const int m = (wq << 4) + (quad << 2) + rg;
    const float rden = 1.0f / DenL[m];
    const int l = t0 + m;
#pragma unroll
    for (int j = 0; j < 3; ++j) if (j < nout) {
      const float val = (accN[j][rg] + accV[j][rg]) * rden;
      Out[((size_t)(n * LSEQ + l)) * DD + h * HD + ((NT0 + j) << 4) + lm] = val;
    }
  }
}

// ---------------------------------------------------------------------------
extern "C" void kernel_launch(void* const* d_in, const int* in_sizes, int n_in,
                              void* d_out, int out_size, void* d_ws, size_t ws_size,
                              hipStream_t stream) {
  (void)in_sizes; (void)n_in; (void)out_size; (void)ws_size;
  const float* query  = (const float*)d_in[0];
  const float* keyseq = (const float*)d_in[1];
  const float* Wq     = (const float*)d_in[2];
  const float* Wk     = (const float*)d_in[3];
  const float* Wv     = (const float*)d_in[4];
  const float* pc     = (const float*)d_in[5];  // position_coeffs (H,d)
  const float* pw     = (const float*)d_in[6];  // position_weight (H,d,1)
  const float* pb     = (const float*)d_in[7];  // position_bias (H,d)
  float* out = (float*)d_out;

  // workspace: bf16 intermediates + bf16 prefix states + bf16 operand copies.
  // (fp32 S buffer eliminated by the fused scan.)
  ushort* Qfb = (ushort*)d_ws;                              // 4 MB
  ushort* Kfb = Qfb + (size_t)NBH * LSEQ * FDIM;            // 4 MB
  ushort* Vxb = Kfb + (size_t)NBH * LSEQ * FDIM;            // 2 MB
  ushort* PTb = Vxb + (size_t)NBH * LSEQ * HD;              // 5.2 MB
  ushort* Xqb  = PTb + (size_t)NBH * NC * SEP * FDIM;       // 2 MB
  ushort* Xkvb = Xqb  + (size_t)NB * LSEQ * DD;             // 2 MB
  ushort* Wqb  = Xkvb + (size_t)NB * LSEQ * DD;             // 512 KB
  ushort* Wkb  = Wqb  + (size_t)DD * DD;                    // 512 KB
  ushort* Wvb  = Wkb  + (size_t)DD * DD;                    // 512 KB

  k_cvt       <<<1408,     256, 0, stream>>>(query, keyseq, Wq, Wk, Wv, Xqb, Xkvb, Wqb, Wkb, Wvb);
  k_proj      <<<768,      256, 0, stream>>>(Xqb, Xkvb, Wqb, Wkb, Wvb, pw, pb, pc, Qfb, Kfb, Vxb);
  k_sums_scan <<<32,       512, 0, stream>>>(Kfb, Vxb, PTb);
  k_chunk_out <<<NBH * NC, 512, 0, stream>>>(Qfb, Kfb, Vxb, PTb, out);
}

// Round 3
// 109.435 us; speedup vs baseline: 1.0926x; 1.0926x over previous
//
#include <hip/hip_runtime.h>
#include <cmath>

// Problem constants (from reference): N=2, Lq=1024, Lk=1024, H=8, d=64, P=1, D=512
#define NB    2
#define LSEQ  1024
#define NH    8
#define HD    64
#define DD    512    // NH*HD
#define FDIM  128    // 2*HD  (cos|sin features)
#define EV    65     // HD + 1 (values + denominator unit column)
#define SEP   80     // padded e-extent of the stored chunk state
#define CHUNK 64
#define NC    16     // LSEQ / CHUNK
#define NBH   16     // NB*NH

typedef short short8 __attribute__((ext_vector_type(8)));   // 8 bf16 (4 VGPRs)
typedef float floatx4 __attribute__((ext_vector_type(4)));  // MFMA C/D frag
typedef unsigned short ushort;

__device__ __forceinline__ float softplusf(float x) {
  return fmaxf(x, 0.0f) + log1pf(expf(-fabsf(x)));
}

__device__ __forceinline__ ushort f2bf(float f) {
  unsigned u = __float_as_uint(f);
  u += 0x7fffu + ((u >> 16) & 1u);
  return (ushort)(u >> 16);
}

__device__ __forceinline__ short8 cvt8(float4 a, float4 b) {
  short8 r;
  r[0] = (short)f2bf(a.x); r[1] = (short)f2bf(a.y);
  r[2] = (short)f2bf(a.z); r[3] = (short)f2bf(a.w);
  r[4] = (short)f2bf(b.x); r[5] = (short)f2bf(b.y);
  r[6] = (short)f2bf(b.z); r[7] = (short)f2bf(b.w);
  return r;
}

// ---------------------------------------------------------------------------
// K0: one-shot fp32 -> bf16 conversion of all GEMM operands.
// 8-float groups: Xq 131072, Xkv 131072, Wq/Wk/Wv 32768 each = 360448 total.
// ---------------------------------------------------------------------------
__global__ __launch_bounds__(256) void k_cvt(
    const float* __restrict__ Xq, const float* __restrict__ Xkv,
    const float* __restrict__ Wq, const float* __restrict__ Wk,
    const float* __restrict__ Wv,
    ushort* __restrict__ Xqb, ushort* __restrict__ Xkvb,
    ushort* __restrict__ Wqb, ushort* __restrict__ Wkb,
    ushort* __restrict__ Wvb)
{
  const int i = blockIdx.x * 256 + threadIdx.x;
  const float* src; ushort* dst; int g;
  if (i < 131072)      { src = Xq;  dst = Xqb;  g = i; }
  else if (i < 262144) { src = Xkv; dst = Xkvb; g = i - 131072; }
  else if (i < 294912) { src = Wq;  dst = Wqb;  g = i - 262144; }
  else if (i < 327680) { src = Wk;  dst = Wkb;  g = i - 294912; }
  else                 { src = Wv;  dst = Wvb;  g = i - 327680; }
  const float4 a = ((const float4*)src)[(size_t)g * 2];
  const float4 b = ((const float4*)src)[(size_t)g * 2 + 1];
  *(short8*)&dst[(size_t)g * 8] = cvt8(a, b);
}

// ---------------------------------------------------------------------------
// K1: ALL projections, bf16 MFMA, K-slice 64, 64x64 tiles, 768 blocks,
// LDS double-buffered, ONE barrier per K-slice, bf16 operands, XCD-chunked
// blockIdx swizzle. (Unchanged from the 111.0 us config.)
// ---------------------------------------------------------------------------
__global__ __launch_bounds__(256) void k_proj(
    const ushort* __restrict__ Xqb, const ushort* __restrict__ Xkvb,
    const ushort* __restrict__ Wqb, const ushort* __restrict__ Wkb,
    const ushort* __restrict__ Wvb,
    const float* __restrict__ pw, const float* __restrict__ pb,
    const float* __restrict__ pc,
    ushort* __restrict__ Qfb, ushort* __restrict__ Kfb,
    ushort* __restrict__ Vxb)
{
  __shared__ short Al[2][64][72];   // [buf][m][k] bf16
  __shared__ short Bl[2][64][72];   // [buf][e][k] bf16
  const int b = ((blockIdx.x & 7) * 96) + (blockIdx.x >> 3);
  int m0, e0, pmode;             // 0 = q, 1 = k, 2 = v
  const ushort *X, *W;
  if (b < 256) {
    m0 = (b >> 3) << 6; e0 = (b & 7) << 6;
    X = Xqb; W = Wqb + (size_t)e0 * DD; pmode = 0;
  } else {
    const int bb = b - 256;
    m0 = (bb >> 4) << 6;
    const int nt = bb & 15;
    e0 = (nt & 7) << 6;
    X = Xkvb;
    if (nt < 8) { W = Wkb + (size_t)e0 * DD; pmode = 1; }
    else        { W = Wvb + (size_t)e0 * DD; pmode = 2; }
  }
  const int tid  = threadIdx.x;
  const int r    = tid >> 2;               // staging row 0..63
  const int ko   = (tid & 3) << 4;         // 0,16,32,48 shorts
  const int wave = tid >> 6, lane = tid & 63;
  const int quad = lane >> 4, lm = lane & 15;
  const ushort* Ag = X + (size_t)(m0 + r) * DD + ko;
  const ushort* Bg = W + (size_t)r * DD + ko;

  short8 a0 = *(const short8*)(Ag);
  short8 a1 = *(const short8*)(Ag + 8);
  short8 b0 = *(const short8*)(Bg);
  short8 b1 = *(const short8*)(Bg + 8);
  *(short8*)&Al[0][r][ko]     = a0;
  *(short8*)&Al[0][r][ko + 8] = a1;
  *(short8*)&Bl[0][r][ko]     = b0;
  *(short8*)&Bl[0][r][ko + 8] = b1;
  __syncthreads();

  floatx4 acc[4] = {};
  for (int k0 = 0; k0 < DD; k0 += 64) {
    const int cur  = (k0 >> 6) & 1;
    const bool more = (k0 + 64 < DD);
    if (more) {
      a0 = *(const short8*)(Ag + k0 + 64);
      a1 = *(const short8*)(Ag + k0 + 72);
      b0 = *(const short8*)(Bg + k0 + 64);
      b1 = *(const short8*)(Bg + k0 + 72);
    }
#pragma unroll
    for (int ks = 0; ks < 2; ++ks) {
      const short8 af = *(const short8*)&Al[cur][(wave << 4) + lm][(quad << 3) + (ks << 5)];
#pragma unroll
      for (int t = 0; t < 4; ++t) {
        const short8 bf = *(const short8*)&Bl[cur][(t << 4) + lm][(quad << 3) + (ks << 5)];
        acc[t] = __builtin_amdgcn_mfma_f32_16x16x32_bf16(af, bf, acc[t], 0, 0, 0);
      }
    }
    if (more) {
      const int nxt = cur ^ 1;
      *(short8*)&Al[nxt][r][ko]     = a0;
      *(short8*)&Al[nxt][r][ko + 8] = a1;
      *(short8*)&Bl[nxt][r][ko]     = b0;
      *(short8*)&Bl[nxt][r][ko + 8] = b1;
    }
    __syncthreads();
  }
#pragma unroll
  for (int t = 0; t < 4; ++t) {
    const int e = e0 + (t << 4) + lm;
    const int h = e >> 6, jj = e & 63;
    if (pmode == 2) {
#pragma unroll
      for (int rg = 0; rg < 4; ++rg) {
        const int m = m0 + (wave << 4) + (quad << 2) + rg;
        const int n = m >> 10, l = m & 1023;
        Vxb[((size_t)(n * NH + h) * LSEQ + l) * HD + jj] = f2bf(acc[t][rg]);
      }
    } else {
      const float pwv = pw[e];
      const float pbv = (pmode == 0) ? pb[e] : 0.0f;
      const float pcv = (pmode == 0) ? pc[e] : 1.0f;
      ushort* base = (pmode == 0) ? Qfb : Kfb;
#pragma unroll
      for (int rg = 0; rg < 4; ++rg) {
        const int m = m0 + (wave << 4) + (quad << 2) + rg;
        const int n = m >> 10, l = m & 1023;
        const float v = softplusf(acc[t][rg]) * pcv;
        const float ang = fmaf((float)l, pwv, pbv);
        ushort* dst = &base[((size_t)(n * NH + h) * LSEQ + l) * FDIM + jj];
        dst[0]  = f2bf(v * __cosf(ang));
        dst[64] = f2bf(v * __sinf(ang));
      }
    }
  }
}

// ---------------------------------------------------------------------------
// K2: per-chunk state sums on bf16 MFMA, stored TRANSPOSED + padded fp32:
// S^T[bh*NC+c][e=0..79][f=0..127]. Grid 512: blk = bh*32 + c*2 + fh.
// (Restored from the 111.0 us config — the 32-block fused scan serialized
// 16 chunks on 12.5% of the CUs and regressed +8.5 us.)
// ---------------------------------------------------------------------------
__global__ __launch_bounds__(256) void k_chunk_sums(
    const ushort* __restrict__ Kfb, const ushort* __restrict__ Vxb,
    float* __restrict__ S)
{
  const int blk = blockIdx.x;
  const int bh  = blk >> 5;
  const int c   = (blk >> 1) & (NC - 1);
  const int fh  = blk & 1;
  const int f0  = fh << 6;
  const int t0  = c * CHUNK;
  const int tid  = threadIdx.x;
  const int wave = tid >> 6, lane = tid & 63;
  const int quad = lane >> 4, lm = lane & 15;

  __shared__ short KT[64][72];   // [f-f0][t] bf16  9216 B
  __shared__ short VT[80][72];   // [e][t]    bf16 11520 B

  for (int i = tid; i < 64 * 8; i += 256) {
    const int t = i & 63, f8 = (i >> 6) << 3;
    const short8 k8 = *(const short8*)&Kfb[((size_t)bh * LSEQ + t0 + t) * FDIM + f0 + f8];
#pragma unroll
    for (int u = 0; u < 8; ++u) KT[f8 + u][t] = k8[u];
  }
  for (int i = tid; i < 64 * 8; i += 256) {
    const int t = i & 63, e8 = (i >> 6) << 3;
    const short8 v8 = *(const short8*)&Vxb[((size_t)bh * LSEQ + t0 + t) * HD + e8];
#pragma unroll
    for (int u = 0; u < 8; ++u) VT[e8 + u][t] = v8[u];
  }
  if (tid < CHUNK) VT[64][tid] = (short)0x3F80;   // bf16 1.0
  __syncthreads();

  short8 aK[2];
#pragma unroll
  for (int ks = 0; ks < 2; ++ks)
    aK[ks] = *(const short8*)&KT[(wave << 4) + lm][(quad << 3) + (ks << 5)];
  floatx4 acc[5] = {};
#pragma unroll
  for (int nt = 0; nt < 5; ++nt)
#pragma unroll
    for (int ks = 0; ks < 2; ++ks) {
      const short8 bf = *(const short8*)&VT[(nt << 4) + lm][(quad << 3) + (ks << 5)];
      acc[nt] = __builtin_amdgcn_mfma_f32_16x16x32_bf16(aK[ks], bf, acc[nt], 0, 0, 0);
    }

  float* Sb = &S[(size_t)(bh * NC + c) * SEP * FDIM];
#pragma unroll
  for (int nt = 0; nt < 4; ++nt)
#pragma unroll
    for (int rg = 0; rg < 4; ++rg) {
      const int f = f0 + (wave << 4) + (quad << 2) + rg;
      Sb[((nt << 4) + lm) * FDIM + f] = acc[nt][rg];
    }
  if (lm == 0) {
#pragma unroll
    for (int rg = 0; rg < 4; ++rg) {
      const int f = f0 + (wave << 4) + (quad << 2) + rg;
      Sb[64 * FDIM + f] = acc[4][rg];
    }
  }
}

// ---------------------------------------------------------------------------
// K3: exclusive prefix scan over the NC chunk states per bh (ILP-16 loads,
// fp32 accumulate, bf16 B-frag-layout output). Grid NBH*13. (Restored.)
// ---------------------------------------------------------------------------
__global__ __launch_bounds__(256) void k_scan(
    const float* __restrict__ S, ushort* __restrict__ PTb)
{
  const int bh = blockIdx.x / 13;
  const int eg = blockIdx.x % 13;          // 13 groups of 5 e-rows (65 total)
  const size_t cs = (size_t)SEP * FDIM;    // chunk stride (elements)
  const float* Sg = S + (size_t)bh * NC * cs;
  ushort* Pg = PTb + (size_t)bh * NC * cs;
  for (int i = threadIdx.x; i < 5 * FDIM; i += 256) {
    const int e = eg * 5 + (i >> 7);
    const int f = i & 127;
    const int off = e * FDIM + f;
    float v[NC];
#pragma unroll
    for (int c = 0; c < NC; ++c) v[c] = Sg[(size_t)c * cs + off];
    float s = 0.0f;
#pragma unroll
    for (int c = 0; c < NC; ++c) {
      Pg[(size_t)c * cs + off] = f2bf(s);
      s += v[c];
    }
  }
}

// ---------------------------------------------------------------------------
// K4: per-chunk output, 512 threads / 8 waves (kept from round 2 — verified
// correct there): wq=wave&3 owns 16 q-rows, wn=wave>>2 splits output tiles
// (phase1 nt {0,1}/{2,3}; phases 2-3 nt {0,1,2}/{3,4}). Shared LDS staging,
// per-wave MFMA work halved, 2x waves hiding the ~68 KB staging latency
// (this kernel is latency-bound: 256 blocks = 1/CU, MFMA phases are tiny).
// ---------------------------------------------------------------------------
__global__ __launch_bounds__(512) void k_chunk_out(
    const ushort* __restrict__ Qfb, const ushort* __restrict__ Kfb,
    const ushort* __restrict__ Vxb, const ushort* __restrict__ PTb,
    float* __restrict__ Out)
{
  const int c  = blockIdx.x & (NC - 1);
  const int bh = blockIdx.x >> 4;
  const int n  = bh >> 3, h = bh & 7;
  const int t0 = c * CHUNK;
  const int tid  = threadIdx.x;
  const int wave = tid >> 6, lane = tid & 63;
  const int quad = lane >> 4, lm = lane & 15;
  const int wq = wave & 3, wn = wave >> 2;

  __shared__ short QL[64][136];    // [t][f] bf16 (pad: 2-way banks)
  __shared__ short KL[64][136];    // [t][f] bf16
  __shared__ short ScL[64][72];    // [m][t] bf16
  __shared__ short PT[80][136];    // [e][f] bf16
  __shared__ short VT[80][72];     // [e][t] bf16
  __shared__ float DenL[64];

  const ushort* Qg = &Qfb[((size_t)bh * LSEQ + t0) * FDIM];
  const ushort* Kg = &Kfb[((size_t)bh * LSEQ + t0) * FDIM];
  for (int i = tid; i < 64 * 16; i += 512) {
    const int r = i >> 4, f8 = (i & 15) << 3;
    *(short8*)&QL[r][f8] = *(const short8*)&Qg[r * FDIM + f8];
    *(short8*)&KL[r][f8] = *(const short8*)&Kg[r * FDIM + f8];
  }
  {
    const ushort* Pg = &PTb[(size_t)(bh * NC + c) * SEP * FDIM];
    for (int i = tid; i < 65 * 16; i += 512) {
      const int e = i >> 4, f8 = (i & 15) << 3;
      *(short8*)&PT[e][f8] = *(const short8*)&Pg[e * FDIM + f8];
    }
  }
  for (int i = tid; i < 64 * 8; i += 512) {
    const int t = i & 63, e8 = (i >> 6) << 3;
    const short8 v8 = *(const short8*)&Vxb[((size_t)bh * LSEQ + t0 + t) * HD + e8];
#pragma unroll
    for (int u = 0; u < 8; ++u) VT[e8 + u][t] = v8[u];
  }
  if (tid < CHUNK) VT[64][tid] = (short)0x3F80;   // bf16 1.0
  __syncthreads();

  short8 aQ[4];
#pragma unroll
  for (int ks = 0; ks < 4; ++ks)
    aQ[ks] = *(const short8*)&QL[(wq << 4) + lm][(quad << 3) + (ks << 5)];

  // phase 1: scores; wave owns t-tiles nt = wn*2 + j
  floatx4 accS[2] = {};
#pragma unroll
  for (int j = 0; j < 2; ++j)
#pragma unroll
    for (int ks = 0; ks < 4; ++ks) {
      const short8 b = *(const short8*)&KL[(((wn << 1) + j) << 4) + lm][(quad << 3) + (ks << 5)];
      accS[j] = __builtin_amdgcn_mfma_f32_16x16x32_bf16(aQ[ks], b, accS[j], 0, 0, 0);
    }
#pragma unroll
  for (int j = 0; j < 2; ++j)
#pragma unroll
    for (int rg = 0; rg < 4; ++rg) {
      const int m = (wq << 4) + (quad << 2) + rg;
      const int t = (((wn << 1) + j) << 4) + lm;
      ScL[m][t] = (short)((t <= m) ? f2bf(accS[j][rg]) : 0);
    }

  // phase 2: num = Q @ P; wave owns e-tiles NT0..NT0+NTN-1 (no ScL dep)
  const int NT0 = wn ? 3 : 0;
  const int NTN = wn ? 2 : 3;
  floatx4 accN[3] = {};
#pragma unroll
  for (int j = 0; j < 3; ++j) if (j < NTN)
#pragma unroll
    for (int ks = 0; ks < 4; ++ks) {
      const short8 b = *(const short8*)&PT[((NT0 + j) << 4) + lm][(quad << 3) + (ks << 5)];
      accN[j] = __builtin_amdgcn_mfma_f32_16x16x32_bf16(aQ[ks], b, accN[j], 0, 0, 0);
    }

  __syncthreads();   // ScL now complete across waves

  // phase 3: PV = Sc @ Vext, same e-tile split as phase 2
  short8 aS[2];
#pragma unroll
  for (int ks = 0; ks < 2; ++ks)
    aS[ks] = *(const short8*)&ScL[(wq << 4) + lm][(quad << 3) + (ks << 5)];
  floatx4 accV[3] = {};
#pragma unroll
  for (int j = 0; j < 3; ++j) if (j < NTN)
#pragma unroll
    for (int ks = 0; ks < 2; ++ks) {
      const short8 b = *(const short8*)&VT[((NT0 + j) << 4) + lm][(quad << 3) + (ks << 5)];
      accV[j] = __builtin_amdgcn_mfma_f32_16x16x32_bf16(aS[ks], b, accV[j], 0, 0, 0);
    }

  // denominator tile is nt=4 -> wn==1, local j==1
  if (wn == 1 && lm == 0) {
#pragma unroll
    for (int rg = 0; rg < 4; ++rg)
      DenL[(wq << 4) + (quad << 2) + rg] = accN[1][rg] + accV[1][rg];
  }
  __syncthreads();   // DenL cross-wave

  const int nout = wn ? 1 : 3;   // wn0 writes nt 0,1,2; wn1 writes nt 3
#pragma unroll
  for (int rg = 0; rg < 4; ++rg) {
    const int m = (wq << 4) + (quad << 2) + rg;
    const float rden = 1.0f / DenL[m];
    const int l = t0 + m;
#pragma unroll
    for (int j = 0; j < 3; ++j) if (j < nout) {
      const float val = (accN[j][rg] + accV[j][rg]) * rden;
      Out[((size_t)(n * LSEQ + l)) * DD + h * HD + ((NT0 + j) << 4) + lm] = val;
    }
  }
}

// ---------------------------------------------------------------------------
extern "C" void kernel_launch(void* const* d_in, const int* in_sizes, int n_in,
                              void* d_out, int out_size, void* d_ws, size_t ws_size,
                              hipStream_t stream) {
  (void)in_sizes; (void)n_in; (void)out_size; (void)ws_size;
  const float* query  = (const float*)d_in[0];
  const float* keyseq = (const float*)d_in[1];
  const float* Wq     = (const float*)d_in[2];
  const float* Wk     = (const float*)d_in[3];
  const float* Wv     = (const float*)d_in[4];
  const float* pc     = (const float*)d_in[5];  // position_coeffs (H,d)
  const float* pw     = (const float*)d_in[6];  // position_weight (H,d,1)
  const float* pb     = (const float*)d_in[7];  // position_bias (H,d)
  float* out = (float*)d_out;

  // workspace: bf16 intermediates (row layouts), fp32 chunk states, bf16 prefix,
  // then one-shot bf16 copies of the GEMM operands.
  ushort* Qfb = (ushort*)d_ws;                            // 4 MB
  ushort* Kfb = Qfb + (size_t)NBH * LSEQ * FDIM;          // 4 MB
  ushort* Vxb = Kfb + (size_t)NBH * LSEQ * FDIM;          // 2 MB
  float*  S   = (float*)(Vxb + (size_t)NBH * LSEQ * HD);  // 10.5 MB
  ushort* PTb = (ushort*)(S + (size_t)NBH * NC * SEP * FDIM); // 5.2 MB
  ushort* Xqb  = PTb + (size_t)NBH * NC * SEP * FDIM;     // 2 MB
  ushort* Xkvb = Xqb  + (size_t)NB * LSEQ * DD;           // 2 MB
  ushort* Wqb  = Xkvb + (size_t)NB * LSEQ * DD;           // 512 KB
  ushort* Wkb  = Wqb  + (size_t)DD * DD;                  // 512 KB
  ushort* Wvb  = Wkb  + (size_t)DD * DD;                  // 512 KB

  k_cvt       <<<1408,         256, 0, stream>>>(query, keyseq, Wq, Wk, Wv, Xqb, Xkvb, Wqb, Wkb, Wvb);
  k_proj      <<<768,          256, 0, stream>>>(Xqb, Xkvb, Wqb, Wkb, Wvb, pw, pb, pc, Qfb, Kfb, Vxb);
  k_chunk_sums<<<NBH * NC * 2, 256, 0, stream>>>(Kfb, Vxb, S);
  k_scan      <<<NBH * 13,     256, 0, stream>>>(S, PTb);
  k_chunk_out <<<NBH * NC,     512, 0, stream>>>(Qfb, Kfb, Vxb, PTb, out);
}

// Round 4
// 109.419 us; speedup vs baseline: 1.0928x; 1.0002x over previous
//
#include <hip/hip_runtime.h>
#include <cmath>

// Problem constants (from reference): N=2, Lq=1024, Lk=1024, H=8, d=64, P=1, D=512
#define NB    2
#define LSEQ  1024
#define NH    8
#define HD    64
#define DD    512    // NH*HD
#define FDIM  128    // 2*HD  (cos|sin features)
#define EV    65     // HD + 1 (values + denominator unit column)
#define SEP   80     // padded e-extent of the stored chunk state
#define CHUNK 64
#define NC    16     // LSEQ / CHUNK
#define NBH   16     // NB*NH

typedef short short8 __attribute__((ext_vector_type(8)));   // 8 bf16 (4 VGPRs)
typedef float floatx4 __attribute__((ext_vector_type(4)));  // MFMA C/D frag 16x16
typedef float floatx16 __attribute__((ext_vector_type(16)));// MFMA C/D frag 32x32
typedef unsigned short ushort;

__device__ __forceinline__ float softplusf(float x) {
  return fmaxf(x, 0.0f) + log1pf(expf(-fabsf(x)));
}

__device__ __forceinline__ ushort f2bf(float f) {
  unsigned u = __float_as_uint(f);
  u += 0x7fffu + ((u >> 16) & 1u);
  return (ushort)(u >> 16);
}

__device__ __forceinline__ short8 cvt8(float4 a, float4 b) {
  short8 r;
  r[0] = (short)f2bf(a.x); r[1] = (short)f2bf(a.y);
  r[2] = (short)f2bf(a.z); r[3] = (short)f2bf(a.w);
  r[4] = (short)f2bf(b.x); r[5] = (short)f2bf(b.y);
  r[6] = (short)f2bf(b.z); r[7] = (short)f2bf(b.w);
  return r;
}

// ---------------------------------------------------------------------------
// K0: one-shot fp32 -> bf16 conversion of all GEMM operands.
// 8-float groups: Xq 131072, Xkv 131072, Wq/Wk/Wv 32768 each = 360448 total.
// ---------------------------------------------------------------------------
__global__ __launch_bounds__(256) void k_cvt(
    const float* __restrict__ Xq, const float* __restrict__ Xkv,
    const float* __restrict__ Wq, const float* __restrict__ Wk,
    const float* __restrict__ Wv,
    ushort* __restrict__ Xqb, ushort* __restrict__ Xkvb,
    ushort* __restrict__ Wqb, ushort* __restrict__ Wkb,
    ushort* __restrict__ Wvb)
{
  const int i = blockIdx.x * 256 + threadIdx.x;
  const float* src; ushort* dst; int g;
  if (i < 131072)      { src = Xq;  dst = Xqb;  g = i; }
  else if (i < 262144) { src = Xkv; dst = Xkvb; g = i - 131072; }
  else if (i < 294912) { src = Wq;  dst = Wqb;  g = i - 262144; }
  else if (i < 327680) { src = Wk;  dst = Wkb;  g = i - 294912; }
  else                 { src = Wv;  dst = Wvb;  g = i - 327680; }
  const float4 a = ((const float4*)src)[(size_t)g * 2];
  const float4 b = ((const float4*)src)[(size_t)g * 2 + 1];
  *(short8*)&dst[(size_t)g * 8] = cvt8(a, b);
}

// ---------------------------------------------------------------------------
// K1: ALL projections, bf16 MFMA, K-slice 64, 64x64 tiles, 768 blocks,
// LDS double-buffered, ONE barrier per K-slice, bf16 operands, XCD-chunked
// blockIdx swizzle. NOW: wave tile 32x32 on v_mfma_f32_32x32x16_bf16
// (was 16x64 on 16x16x32): per slice per wave 4A+4B ds_read_b128 + 4 MFMA
// (was 2A+8B + 8 MFMA) -> -20% LDS reads, -20% MFMA issue, VGPR-neutral
// (16 acc floats/lane either way). Epilogue loads pw/pb/pc once per lane.
// ---------------------------------------------------------------------------
__global__ __launch_bounds__(256) void k_proj(
    const ushort* __restrict__ Xqb, const ushort* __restrict__ Xkvb,
    const ushort* __restrict__ Wqb, const ushort* __restrict__ Wkb,
    const ushort* __restrict__ Wvb,
    const float* __restrict__ pw, const float* __restrict__ pb,
    const float* __restrict__ pc,
    ushort* __restrict__ Qfb, ushort* __restrict__ Kfb,
    ushort* __restrict__ Vxb)
{
  __shared__ short Al[2][64][72];   // [buf][m][k] bf16
  __shared__ short Bl[2][64][72];   // [buf][e][k] bf16
  const int b = ((blockIdx.x & 7) * 96) + (blockIdx.x >> 3);
  int m0, e0, pmode;             // 0 = q, 1 = k, 2 = v
  const ushort *X, *W;
  if (b < 256) {
    m0 = (b >> 3) << 6; e0 = (b & 7) << 6;
    X = Xqb; W = Wqb + (size_t)e0 * DD; pmode = 0;
  } else {
    const int bb = b - 256;
    m0 = (bb >> 4) << 6;
    const int nt = bb & 15;
    e0 = (nt & 7) << 6;
    X = Xkvb;
    if (nt < 8) { W = Wkb + (size_t)e0 * DD; pmode = 1; }
    else        { W = Wvb + (size_t)e0 * DD; pmode = 2; }
  }
  const int tid  = threadIdx.x;
  const int r    = tid >> 2;               // staging row 0..63
  const int ko   = (tid & 3) << 4;         // 0,16,32,48 shorts
  const int wave = tid >> 6, lane = tid & 63;
  const int l31  = lane & 31, half = lane >> 5;
  const int rb   = (wave >> 1) << 5;       // wave row base 0/32
  const int cb   = (wave & 1) << 5;        // wave col base 0/32
  const ushort* Ag = X + (size_t)(m0 + r) * DD + ko;
  const ushort* Bg = W + (size_t)r * DD + ko;

  short8 a0 = *(const short8*)(Ag);
  short8 a1 = *(const short8*)(Ag + 8);
  short8 b0 = *(const short8*)(Bg);
  short8 b1 = *(const short8*)(Bg + 8);
  *(short8*)&Al[0][r][ko]     = a0;
  *(short8*)&Al[0][r][ko + 8] = a1;
  *(short8*)&Bl[0][r][ko]     = b0;
  *(short8*)&Bl[0][r][ko + 8] = b1;
  __syncthreads();

  floatx16 acc = {};
  for (int k0 = 0; k0 < DD; k0 += 64) {
    const int cur  = (k0 >> 6) & 1;
    const bool more = (k0 + 64 < DD);
    if (more) {
      a0 = *(const short8*)(Ag + k0 + 64);
      a1 = *(const short8*)(Ag + k0 + 72);
      b0 = *(const short8*)(Bg + k0 + 64);
      b1 = *(const short8*)(Bg + k0 + 72);
    }
#pragma unroll
    for (int ks = 0; ks < 4; ++ks) {
      const short8 af = *(const short8*)&Al[cur][rb + l31][(ks << 4) + (half << 3)];
      const short8 bf = *(const short8*)&Bl[cur][cb + l31][(ks << 4) + (half << 3)];
      acc = __builtin_amdgcn_mfma_f32_32x32x16_bf16(af, bf, acc, 0, 0, 0);
    }
    if (more) {
      const int nxt = cur ^ 1;
      *(short8*)&Al[nxt][r][ko]     = a0;
      *(short8*)&Al[nxt][r][ko + 8] = a1;
      *(short8*)&Bl[nxt][r][ko]     = b0;
      *(short8*)&Bl[nxt][r][ko + 8] = b1;
    }
    __syncthreads();
  }

  // epilogue: C/D layout col = lane&31, row = (reg&3) + 8*(reg>>2) + 4*half
  const int e = e0 + cb + l31;
  const int h = e >> 6, jj = e & 63;
  if (pmode == 2) {
#pragma unroll
    for (int rg = 0; rg < 16; ++rg) {
      const int m = m0 + rb + (rg & 3) + ((rg >> 2) << 3) + (half << 2);
      const int n = m >> 10, l = m & 1023;
      Vxb[((size_t)(n * NH + h) * LSEQ + l) * HD + jj] = f2bf(acc[rg]);
    }
  } else {
    const float pwv = pw[e];
    const float pbv = (pmode == 0) ? pb[e] : 0.0f;
    const float pcv = (pmode == 0) ? pc[e] : 1.0f;
    ushort* base = (pmode == 0) ? Qfb : Kfb;
#pragma unroll
    for (int rg = 0; rg < 16; ++rg) {
      const int m = m0 + rb + (rg & 3) + ((rg >> 2) << 3) + (half << 2);
      const int n = m >> 10, l = m & 1023;
      const float v = softplusf(acc[rg]) * pcv;
      const float ang = fmaf((float)l, pwv, pbv);
      ushort* dst = &base[((size_t)(n * NH + h) * LSEQ + l) * FDIM + jj];
      dst[0]  = f2bf(v * __cosf(ang));
      dst[64] = f2bf(v * __sinf(ang));
    }
  }
}

// ---------------------------------------------------------------------------
// K2: per-chunk state sums on bf16 MFMA, stored TRANSPOSED + padded fp32:
// S^T[bh*NC+c][e=0..79][f=0..127]. Grid 512: blk = bh*32 + c*2 + fh.
// ---------------------------------------------------------------------------
__global__ __launch_bounds__(256) void k_chunk_sums(
    const ushort* __restrict__ Kfb, const ushort* __restrict__ Vxb,
    float* __restrict__ S)
{
  const int blk = blockIdx.x;
  const int bh  = blk >> 5;
  const int c   = (blk >> 1) & (NC - 1);
  const int fh  = blk & 1;
  const int f0  = fh << 6;
  const int t0  = c * CHUNK;
  const int tid  = threadIdx.x;
  const int wave = tid >> 6, lane = tid & 63;
  const int quad = lane >> 4, lm = lane & 15;

  __shared__ short KT[64][72];   // [f-f0][t] bf16  9216 B
  __shared__ short VT[80][72];   // [e][t]    bf16 11520 B

  for (int i = tid; i < 64 * 8; i += 256) {
    const int t = i & 63, f8 = (i >> 6) << 3;
    const short8 k8 = *(const short8*)&Kfb[((size_t)bh * LSEQ + t0 + t) * FDIM + f0 + f8];
#pragma unroll
    for (int u = 0; u < 8; ++u) KT[f8 + u][t] = k8[u];
  }
  for (int i = tid; i < 64 * 8; i += 256) {
    const int t = i & 63, e8 = (i >> 6) << 3;
    const short8 v8 = *(const short8*)&Vxb[((size_t)bh * LSEQ + t0 + t) * HD + e8];
#pragma unroll
    for (int u = 0; u < 8; ++u) VT[e8 + u][t] = v8[u];
  }
  if (tid < CHUNK) VT[64][tid] = (short)0x3F80;   // bf16 1.0
  __syncthreads();

  short8 aK[2];
#pragma unroll
  for (int ks = 0; ks < 2; ++ks)
    aK[ks] = *(const short8*)&KT[(wave << 4) + lm][(quad << 3) + (ks << 5)];
  floatx4 acc[5] = {};
#pragma unroll
  for (int nt = 0; nt < 5; ++nt)
#pragma unroll
    for (int ks = 0; ks < 2; ++ks) {
      const short8 bf = *(const short8*)&VT[(nt << 4) + lm][(quad << 3) + (ks << 5)];
      acc[nt] = __builtin_amdgcn_mfma_f32_16x16x32_bf16(aK[ks], bf, acc[nt], 0, 0, 0);
    }

  float* Sb = &S[(size_t)(bh * NC + c) * SEP * FDIM];
#pragma unroll
  for (int nt = 0; nt < 4; ++nt)
#pragma unroll
    for (int rg = 0; rg < 4; ++rg) {
      const int f = f0 + (wave << 4) + (quad << 2) + rg;
      Sb[((nt << 4) + lm) * FDIM + f] = acc[nt][rg];
    }
  if (lm == 0) {
#pragma unroll
    for (int rg = 0; rg < 4; ++rg) {
      const int f = f0 + (wave << 4) + (quad << 2) + rg;
      Sb[64 * FDIM + f] = acc[4][rg];
    }
  }
}

// ---------------------------------------------------------------------------
// K3: exclusive prefix scan over the NC chunk states per bh (ILP-16 loads,
// fp32 accumulate, bf16 B-frag-layout output). Grid NBH*13.
// ---------------------------------------------------------------------------
__global__ __launch_bounds__(256) void k_scan(
    const float* __restrict__ S, ushort* __restrict__ PTb)
{
  const int bh = blockIdx.x / 13;
  const int eg = blockIdx.x % 13;          // 13 groups of 5 e-rows (65 total)
  const size_t cs = (size_t)SEP * FDIM;    // chunk stride (elements)
  const float* Sg = S + (size_t)bh * NC * cs;
  ushort* Pg = PTb + (size_t)bh * NC * cs;
  for (int i = threadIdx.x; i < 5 * FDIM; i += 256) {
    const int e = eg * 5 + (i >> 7);
    const int f = i & 127;
    const int off = e * FDIM + f;
    float v[NC];
#pragma unroll
    for (int c = 0; c < NC; ++c) v[c] = Sg[(size_t)c * cs + off];
    float s = 0.0f;
#pragma unroll
    for (int c = 0; c < NC; ++c) {
      Pg[(size_t)c * cs + off] = f2bf(s);
      s += v[c];
    }
  }
}

// ---------------------------------------------------------------------------
// K4: per-chunk output, 512 threads / 8 waves: wq=wave&3 owns 16 q-rows,
// wn=wave>>2 splits output tiles (phase1 nt {0,1}/{2,3}; phases 2-3
// nt {0,1,2}/{3,4}). Shared LDS staging, per-wave MFMA work halved, 2x waves
// hiding the ~68 KB staging latency. (Verified config from rounds 2-3.)
// ---------------------------------------------------------------------------
__global__ __launch_bounds__(512) void k_chunk_out(
    const ushort* __restrict__ Qfb, const ushort* __restrict__ Kfb,
    const ushort* __restrict__ Vxb, const ushort* __restrict__ PTb,
    float* __restrict__ Out)
{
  const int c  = blockIdx.x & (NC - 1);
  const int bh = blockIdx.x >> 4;
  const int n  = bh >> 3, h = bh & 7;
  const int t0 = c * CHUNK;
  const int tid  = threadIdx.x;
  const int wave = tid >> 6, lane = tid & 63;
  const int quad = lane >> 4, lm = lane & 15;
  const int wq = wave & 3, wn = wave >> 2;

  __shared__ short QL[64][136];    // [t][f] bf16 (pad: 2-way banks)
  __shared__ short KL[64][136];    // [t][f] bf16
  __shared__ short ScL[64][72];    // [m][t] bf16
  __shared__ short PT[80][136];    // [e][f] bf16
  __shared__ short VT[80][72];     // [e][t] bf16
  __shared__ float DenL[64];

  const ushort* Qg = &Qfb[((size_t)bh * LSEQ + t0) * FDIM];
  const ushort* Kg = &Kfb[((size_t)bh * LSEQ + t0) * FDIM];
  for (int i = tid; i < 64 * 16; i += 512) {
    const int r = i >> 4, f8 = (i & 15) << 3;
    *(short8*)&QL[r][f8] = *(const short8*)&Qg[r * FDIM + f8];
    *(short8*)&KL[r][f8] = *(const short8*)&Kg[r * FDIM + f8];
  }
  {
    const ushort* Pg = &PTb[(size_t)(bh * NC + c) * SEP * FDIM];
    for (int i = tid; i < 65 * 16; i += 512) {
      const int e = i >> 4, f8 = (i & 15) << 3;
      *(short8*)&PT[e][f8] = *(const short8*)&Pg[e * FDIM + f8];
    }
  }
  for (int i = tid; i < 64 * 8; i += 512) {
    const int t = i & 63, e8 = (i >> 6) << 3;
    const short8 v8 = *(const short8*)&Vxb[((size_t)bh * LSEQ + t0 + t) * HD + e8];
#pragma unroll
    for (int u = 0; u < 8; ++u) VT[e8 + u][t] = v8[u];
  }
  if (tid < CHUNK) VT[64][tid] = (short)0x3F80;   // bf16 1.0
  __syncthreads();

  short8 aQ[4];
#pragma unroll
  for (int ks = 0; ks < 4; ++ks)
    aQ[ks] = *(const short8*)&QL[(wq << 4) + lm][(quad << 3) + (ks << 5)];

  // phase 1: scores; wave owns t-tiles nt = wn*2 + j
  floatx4 accS[2] = {};
#pragma unroll
  for (int j = 0; j < 2; ++j)
#pragma unroll
    for (int ks = 0; ks < 4; ++ks) {
      const short8 b = *(const short8*)&KL[(((wn << 1) + j) << 4) + lm][(quad << 3) + (ks << 5)];
      accS[j] = __builtin_amdgcn_mfma_f32_16x16x32_bf16(aQ[ks], b, accS[j], 0, 0, 0);
    }
#pragma unroll
  for (int j = 0; j < 2; ++j)
#pragma unroll
    for (int rg = 0; rg < 4; ++rg) {
      const int m = (wq << 4) + (quad << 2) + rg;
      const int t = (((wn << 1) + j) << 4) + lm;
      ScL[m][t] = (short)((t <= m) ? f2bf(accS[j][rg]) : 0);
    }

  // phase 2: num = Q @ P; wave owns e-tiles NT0..NT0+NTN-1 (no ScL dep)
  const int NT0 = wn ? 3 : 0;
  const int NTN = wn ? 2 : 3;
  floatx4 accN[3] = {};
#pragma unroll
  for (int j = 0; j < 3; ++j) if (j < NTN)
#pragma unroll
    for (int ks = 0; ks < 4; ++ks) {
      const short8 b = *(const short8*)&PT[((NT0 + j) << 4) + lm][(quad << 3) + (ks << 5)];
      accN[j] = __builtin_amdgcn_mfma_f32_16x16x32_bf16(aQ[ks], b, accN[j], 0, 0, 0);
    }

  __syncthreads();   // ScL now complete across waves

  // phase 3: PV = Sc @ Vext, same e-tile split as phase 2
  short8 aS[2];
#pragma unroll
  for (int ks = 0; ks < 2; ++ks)
    aS[ks] = *(const short8*)&ScL[(wq << 4) + lm][(quad << 3) + (ks << 5)];
  floatx4 accV[3] = {};
#pragma unroll
  for (int j = 0; j < 3; ++j) if (j < NTN)
#pragma unroll
    for (int ks = 0; ks < 2; ++ks) {
      const short8 b = *(const short8*)&VT[((NT0 + j) << 4) + lm][(quad << 3) + (ks << 5)];
      accV[j] = __builtin_amdgcn_mfma_f32_16x16x32_bf16(aS[ks], b, accV[j], 0, 0, 0);
    }

  // denominator tile is nt=4 -> wn==1, local j==1
  if (wn == 1 && lm == 0) {
#pragma unroll
    for (int rg = 0; rg < 4; ++rg)
      DenL[(wq << 4) + (quad << 2) + rg] = accN[1][rg] + accV[1][rg];
  }
  __syncthreads();   // DenL cross-wave

  const int nout = wn ? 1 : 3;   // wn0 writes nt 0,1,2; wn1 writes nt 3
#pragma unroll
  for (int rg = 0; rg < 4; ++rg) {
    const int m = (wq << 4) + (quad << 2) + rg;
    const float rden = 1.0f / DenL[m];
    const int l = t0 + m;
#pragma unroll
    for (int j = 0; j < 3; ++j) if (j < nout) {
      const float val = (accN[j][rg] + accV[j][rg]) * rden;
      Out[((size_t)(n * LSEQ + l)) * DD + h * HD + ((NT0 + j) << 4) + lm] = val;
    }
  }
}

// ---------------------------------------------------------------------------
extern "C" void kernel_launch(void* const* d_in, const int* in_sizes, int n_in,
                              void* d_out, int out_size, void* d_ws, size_t ws_size,
                              hipStream_t stream) {
  (void)in_sizes; (void)n_in; (void)out_size; (void)ws_size;
  const float* query  = (const float*)d_in[0];
  const float* keyseq = (const float*)d_in[1];
  const float* Wq     = (const float*)d_in[2];
  const float* Wk     = (const float*)d_in[3];
  const float* Wv     = (const float*)d_in[4];
  const float* pc     = (const float*)d_in[5];  // position_coeffs (H,d)
  const float* pw     = (const float*)d_in[6];  // position_weight (H,d,1)
  const float* pb     = (const float*)d_in[7];  // position_bias (H,d)
  float* out = (float*)d_out;

  // workspace: bf16 intermediates (row layouts), fp32 chunk states, bf16 prefix,
  // then one-shot bf16 copies of the GEMM operands.
  ushort* Qfb = (ushort*)d_ws;                            // 4 MB
  ushort* Kfb = Qfb + (size_t)NBH * LSEQ * FDIM;          // 4 MB
  ushort* Vxb = Kfb + (size_t)NBH * LSEQ * FDIM;          // 2 MB
  float*  S   = (float*)(Vxb + (size_t)NBH * LSEQ * HD);  // 10.5 MB
  ushort* PTb = (ushort*)(S + (size_t)NBH * NC * SEP * FDIM); // 5.2 MB
  ushort* Xqb  = PTb + (size_t)NBH * NC * SEP * FDIM;     // 2 MB
  ushort* Xkvb = Xqb  + (size_t)NB * LSEQ * DD;           // 2 MB
  ushort* Wqb  = Xkvb + (size_t)NB * LSEQ * DD;           // 512 KB
  ushort* Wkb  = Wqb  + (size_t)DD * DD;                  // 512 KB
  ushort* Wvb  = Wkb  + (size_t)DD * DD;                  // 512 KB

  k_cvt       <<<1408,         256, 0, stream>>>(query, keyseq, Wq, Wk, Wv, Xqb, Xkvb, Wqb, Wkb, Wvb);
  k_proj      <<<768,          256, 0, stream>>>(Xqb, Xkvb, Wqb, Wkb, Wvb, pw, pb, pc, Qfb, Kfb, Vxb);
  k_chunk_sums<<<NBH * NC * 2, 256, 0, stream>>>(Kfb, Vxb, S);
  k_scan      <<<NBH * 13,     256, 0, stream>>>(S, PTb);
  k_chunk_out <<<NBH * NC,     512, 0, stream>>>(Qfb, Kfb, Vxb, PTb, out);
}